// Round 1
// baseline (976.102 us; speedup 1.0000x reference)
//
#include <hip/hip_runtime.h>

#define BN_EPS 1e-5f

// ---------------- degree / norm ----------------

__global__ void deg_init(float* __restrict__ deg, int n) {
    int i = blockIdx.x * 256 + threadIdx.x;
    if (i < n) deg[i] = 1.0f;  // self-loop
}

__global__ void deg_edges(const int* __restrict__ dst, float* __restrict__ deg, int E) {
    int e = blockIdx.x * 256 + threadIdx.x;
    if (e < E) atomicAdd(&deg[dst[e]], 1.0f);
}

__global__ void deg_rsqrt(float* __restrict__ deg, int n) {
    int i = blockIdx.x * 256 + threadIdx.x;
    if (i < n) deg[i] = rsqrtf(deg[i]);
}

// ---------------- skinny GEMM: H[n,64] = X[n,64] @ W[64,64] ----------------
// 16 rows per 256-thread block; W staged in LDS.

__global__ __launch_bounds__(256) void gemm64(const float* __restrict__ X,
                                              const float* __restrict__ W,
                                              float* __restrict__ H, int n) {
    __shared__ float sW[64 * 64];
    __shared__ float sX[16 * 64];
    int t = threadIdx.x;
    for (int i = t; i < 64 * 64; i += 256) sW[i] = W[i];
    int j = t & 63;
    int r0 = t >> 6;  // 0..3
    int base = blockIdx.x * 16;
    for (int i = t; i < 16 * 64; i += 256) {
        int row = base + (i >> 6);
        sX[i] = (row < n) ? X[(size_t)row * 64 + (i & 63)] : 0.f;
    }
    __syncthreads();
    float acc[4] = {0.f, 0.f, 0.f, 0.f};
#pragma unroll
    for (int k = 0; k < 64; ++k) {
        float w = sW[k * 64 + j];
#pragma unroll
        for (int u = 0; u < 4; ++u)
            acc[u] += sX[(r0 + 4 * u) * 64 + k] * w;
    }
#pragma unroll
    for (int u = 0; u < 4; ++u) {
        int row = base + r0 + 4 * u;
        if (row < n) H[(size_t)row * 64 + j] = acc[u];
    }
}

// ---------------- scatter-aggregate: Y[dst] += H[src] * dinv[src]*dinv[dst] ----------------
// one wave (64 lanes) per entry; entries [0,E) = edges, [E, E+n) = self loops.

__global__ __launch_bounds__(256) void scatter_agg(const float* __restrict__ H,
                                                   const int* __restrict__ src,
                                                   const int* __restrict__ dst,
                                                   const float* __restrict__ dinv,
                                                   float* __restrict__ Y,
                                                   int E, int n) {
    long long e = (long long)blockIdx.x * 4 + (threadIdx.x >> 6);
    int lane = threadIdx.x & 63;
    long long M = (long long)E + n;
    if (e >= M) return;
    int s, d;
    if (e < E) { s = src[e]; d = dst[e]; }
    else       { s = d = (int)(e - E); }
    float nrm = dinv[s] * dinv[d];
    float v = H[(size_t)s * 64 + lane] * nrm;
    atomicAdd(&Y[(size_t)d * 64 + lane], v);
}

// ---------------- BN stats: per-column sum and sumsq ----------------

__global__ __launch_bounds__(256) void bn_stats(const float* __restrict__ Y,
                                                float* __restrict__ stats, int n) {
    int t = threadIdx.x;
    int j = t & 63;
    int rg = t >> 6;
    float s = 0.f, s2 = 0.f;
    for (int i = blockIdx.x * 4 + rg; i < n; i += gridDim.x * 4) {
        float v = Y[(size_t)i * 64 + j];
        s += v;
        s2 += v * v;
    }
    __shared__ float red[256], red2[256];
    red[t] = s;
    red2[t] = s2;
    __syncthreads();
    if (rg == 0) {
        s  = red[j]  + red[64 + j]  + red[128 + j]  + red[192 + j];
        s2 = red2[j] + red2[64 + j] + red2[128 + j] + red2[192 + j];
        atomicAdd(&stats[j], s);
        atomicAdd(&stats[64 + j], s2);
    }
}

// ---------------- BN apply (+ optional ReLU) ----------------

__global__ __launch_bounds__(256) void bn_apply(const float* __restrict__ Y,
                                                const float* __restrict__ stats,
                                                const float* __restrict__ gamma,
                                                const float* __restrict__ beta,
                                                float* __restrict__ X, int n, int relu) {
    size_t idx = (size_t)blockIdx.x * 256 + threadIdx.x;
    if (idx >= (size_t)n * 64) return;
    int j = (int)(idx & 63);
    float inv_n = 1.0f / (float)n;
    float mean = stats[j] * inv_n;
    float var = stats[64 + j] * inv_n - mean * mean;
    float sc = gamma[j] * rsqrtf(var + BN_EPS);
    float sh = beta[j] - mean * sc;
    float v = Y[idx] * sc + sh;
    if (relu) v = fmaxf(v, 0.f);
    X[idx] = v;
}

// ---------------- global mean pool (batch sorted): segmented sum ----------------

__global__ __launch_bounds__(256) void pool_sum(const float* __restrict__ H,
                                                const int* __restrict__ batch,
                                                float* __restrict__ out,
                                                float* __restrict__ cnt, int n) {
    const int CHUNK = 128;
    int w = blockIdx.x * 4 + (threadIdx.x >> 6);
    int lane = threadIdx.x & 63;
    int start = w * CHUNK;
    if (start >= n) return;
    int end = min(start + CHUNK, n);
    int cur = batch[start];
    float acc = 0.f;
    int run = 0;
    for (int i = start; i < end; ++i) {
        int g = batch[i];
        if (g != cur) {
            atomicAdd(&out[(size_t)cur * 64 + lane], acc);
            if (lane == 0) atomicAdd(&cnt[cur], (float)run);
            acc = 0.f;
            run = 0;
            cur = g;
        }
        acc += H[(size_t)i * 64 + lane];
        run++;
    }
    atomicAdd(&out[(size_t)cur * 64 + lane], acc);
    if (lane == 0) atomicAdd(&cnt[cur], (float)run);
}

__global__ void pool_div(float* __restrict__ out, const float* __restrict__ cnt, int G) {
    int idx = blockIdx.x * 256 + threadIdx.x;
    if (idx < G * 64) out[idx] /= fmaxf(cnt[idx >> 6], 1.0f);
}

// ---------------- launch ----------------

extern "C" void kernel_launch(void* const* d_in, const int* in_sizes, int n_in,
                              void* d_out, int out_size, void* d_ws, size_t ws_size,
                              hipStream_t stream) {
    const float* x     = (const float*)d_in[0];
    const int*   ei    = (const int*)d_in[1];
    const int*   batch = (const int*)d_in[2];
    const float* Wl[3] = {(const float*)d_in[3], (const float*)d_in[7], (const float*)d_in[11]};
    const float* gl[3] = {(const float*)d_in[5], (const float*)d_in[9], (const float*)d_in[13]};
    const float* bl[3] = {(const float*)d_in[6], (const float*)d_in[10], (const float*)d_in[14]};
    float* out = (float*)d_out;

    int E = in_sizes[1] / 2;
    int n = in_sizes[0] / 64;
    int G = out_size / 64;
    const int* src = ei;
    const int* dst = ei + E;

    float* ws = (float*)d_ws;
    size_t off = 0;
    float* deg = ws;            off += ((size_t)n + 63) & ~(size_t)63;
    float* stats = ws + off;    off += 128;
    float* cnt = ws + off;      off += ((size_t)G + 63) & ~(size_t)63;
    float* bufA = ws + off;     off += (size_t)n * 64;
    float* bufB = ws + off;

    // degrees -> dinv
    deg_init<<<(n + 255) / 256, 256, 0, stream>>>(deg, n);
    deg_edges<<<(E + 255) / 256, 256, 0, stream>>>(dst, deg, E);
    deg_rsqrt<<<(n + 255) / 256, 256, 0, stream>>>(deg, n);

    const float* cur = x;
    long long M = (long long)E + n;
    for (int l = 0; l < 3; ++l) {
        float* H = (l & 1) ? bufB : bufA;
        float* Y = (l & 1) ? bufA : bufB;
        float* Xo = H;  // H is consumed by scatter before BN writes
        gemm64<<<(n + 15) / 16, 256, 0, stream>>>(cur, Wl[l], H, n);
        hipMemsetAsync(Y, 0, (size_t)n * 64 * sizeof(float), stream);
        scatter_agg<<<(int)((M + 3) / 4), 256, 0, stream>>>(H, src, dst, deg, Y, E, n);
        hipMemsetAsync(stats, 0, 128 * sizeof(float), stream);
        bn_stats<<<256, 256, 0, stream>>>(Y, stats, n);
        bn_apply<<<(int)(((size_t)n * 64 + 255) / 256), 256, 0, stream>>>(
            Y, stats, gl[l], bl[l], Xo, n, l < 2 ? 1 : 0);
        cur = Xo;
    }

    hipMemsetAsync(out, 0, (size_t)G * 64 * sizeof(float), stream);
    hipMemsetAsync(cnt, 0, (size_t)G * sizeof(float), stream);
    int waves = (n + 127) / 128;
    pool_sum<<<(waves + 3) / 4, 256, 0, stream>>>(cur, batch, out, cnt, n);
    pool_div<<<(G * 64 + 255) / 256, 256, 0, stream>>>(out, cnt, G);
}

// Round 2
// 598.128 us; speedup vs baseline: 1.6319x; 1.6319x over previous
//
#include <hip/hip_runtime.h>

#define BN_EPS 1e-5f

// ================= CSR build =================

__global__ void zero_i32(int* __restrict__ p, int n) {
    int i = blockIdx.x * 256 + threadIdx.x;
    if (i < n) p[i] = 0;
}

__global__ void hist_dst(const int* __restrict__ dst, int* __restrict__ cnt, int E) {
    int e = blockIdx.x * 256 + threadIdx.x;
    if (e < E) atomicAdd(&cnt[dst[e]], 1);
}

// dinv[i] = rsqrt(1 + in_degree)  (self-loop included)
__global__ void make_dinv(const int* __restrict__ cnt, float* __restrict__ dinv, int n) {
    int i = blockIdx.x * 256 + threadIdx.x;
    if (i < n) dinv[i] = rsqrtf(1.0f + (float)cnt[i]);
}

// exclusive scan, 256 elems/block (n <= 65536)
__global__ __launch_bounds__(256) void scan1(const int* __restrict__ cnt, int* __restrict__ rp,
                                             int* __restrict__ bsum, int n) {
    __shared__ int s[256];
    int i = blockIdx.x * 256 + threadIdx.x;
    int v = (i < n) ? cnt[i] : 0;
    s[threadIdx.x] = v;
    __syncthreads();
    for (int off = 1; off < 256; off <<= 1) {
        int t = (threadIdx.x >= off) ? s[threadIdx.x - off] : 0;
        __syncthreads();
        s[threadIdx.x] += t;
        __syncthreads();
    }
    if (i < n) rp[i] = s[threadIdx.x] - v;  // exclusive
    if (threadIdx.x == 255) bsum[blockIdx.x] = s[255];
}

__global__ __launch_bounds__(256) void scan2(int* __restrict__ bsum, int nb) {
    __shared__ int s[256];
    int v = (threadIdx.x < nb) ? bsum[threadIdx.x] : 0;
    s[threadIdx.x] = v;
    __syncthreads();
    for (int off = 1; off < 256; off <<= 1) {
        int t = (threadIdx.x >= off) ? s[threadIdx.x - off] : 0;
        __syncthreads();
        s[threadIdx.x] += t;
        __syncthreads();
    }
    if (threadIdx.x < nb) bsum[threadIdx.x] = s[threadIdx.x] - v;  // exclusive
}

__global__ void scan3(int* __restrict__ rp, const int* __restrict__ bsum,
                      int* __restrict__ cursor, int n, int E) {
    int i = blockIdx.x * 256 + threadIdx.x;
    if (i < n) {
        int v = rp[i] + bsum[blockIdx.x];
        rp[i] = v;
        cursor[i] = v;
    }
    if (i == 0) rp[n] = E;
}

__global__ void scatter_col(const int* __restrict__ src, const int* __restrict__ dst,
                            int* __restrict__ cursor, int* __restrict__ col, int E) {
    int e = blockIdx.x * 256 + threadIdx.x;
    if (e < E) {
        int pos = atomicAdd(&cursor[dst[e]], 1);
        col[pos] = src[e];
    }
}

// ================= skinny GEMM with dinv-scaled epilogue =================
// Hs[row] = (X[row] @ W) * dinv[row]

__global__ __launch_bounds__(256) void gemm64(const float* __restrict__ X,
                                              const float* __restrict__ W,
                                              const float* __restrict__ dinv,
                                              float* __restrict__ Hs, int n) {
    __shared__ float sW[64 * 64];
    __shared__ float sX[16 * 64];
    int t = threadIdx.x;
    for (int i = t; i < 64 * 64; i += 256) sW[i] = W[i];
    int j = t & 63;
    int r0 = t >> 6;  // 0..3
    int base = blockIdx.x * 16;
    for (int i = t; i < 16 * 64; i += 256) {
        int row = base + (i >> 6);
        sX[i] = (row < n) ? X[(size_t)row * 64 + (i & 63)] : 0.f;
    }
    __syncthreads();
    float acc[4] = {0.f, 0.f, 0.f, 0.f};
#pragma unroll
    for (int k = 0; k < 64; ++k) {
        float w = sW[k * 64 + j];
#pragma unroll
        for (int u = 0; u < 4; ++u)
            acc[u] += sX[(r0 + 4 * u) * 64 + k] * w;
    }
#pragma unroll
    for (int u = 0; u < 4; ++u) {
        int row = base + r0 + 4 * u;
        if (row < n) Hs[(size_t)row * 64 + j] = acc[u] * dinv[row];
    }
}

// ================= CSR gather-aggregate =================
// Y[d] = dinv[d] * (Hs[d] + sum_{s in N(d)} Hs[s])
// one wave per node; edge indices loaded coalesced, broadcast via shfl.

__global__ __launch_bounds__(256) void agg(const float* __restrict__ Hs,
                                           const int* __restrict__ rp,
                                           const int* __restrict__ col,
                                           const float* __restrict__ dinv,
                                           float* __restrict__ Y, int n) {
    int d = blockIdx.x * 4 + (threadIdx.x >> 6);
    int lane = threadIdx.x & 63;
    if (d >= n) return;
    float acc = Hs[(size_t)d * 64 + lane];  // self loop (dinv[d] applied at end)
    int beg = rp[d], end = rp[d + 1];
    for (int b = beg; b < end; b += 64) {
        int m = min(64, end - b);
        int myidx = (lane < m) ? col[b + lane] : 0;
        int jj = 0;
        for (; jj + 1 < m; jj += 2) {
            int s0 = __shfl(myidx, jj, 64);
            int s1 = __shfl(myidx, jj + 1, 64);
            float v0 = Hs[(size_t)s0 * 64 + lane];
            float v1 = Hs[(size_t)s1 * 64 + lane];
            acc += v0;
            acc += v1;
        }
        if (jj < m) {
            int s0 = __shfl(myidx, jj, 64);
            acc += Hs[(size_t)s0 * 64 + lane];
        }
    }
    Y[(size_t)d * 64 + lane] = acc * dinv[d];
}

// ================= BN stats =================

__global__ __launch_bounds__(256) void bn_stats(const float* __restrict__ Y,
                                                float* __restrict__ stats, int n) {
    int t = threadIdx.x;
    int j = t & 63;
    int rg = t >> 6;
    float s = 0.f, s2 = 0.f;
    for (int i = blockIdx.x * 4 + rg; i < n; i += gridDim.x * 4) {
        float v = Y[(size_t)i * 64 + j];
        s += v;
        s2 += v * v;
    }
    __shared__ float red[256], red2[256];
    red[t] = s;
    red2[t] = s2;
    __syncthreads();
    if (rg == 0) {
        s  = red[j]  + red[64 + j]  + red[128 + j]  + red[192 + j];
        s2 = red2[j] + red2[64 + j] + red2[128 + j] + red2[192 + j];
        atomicAdd(&stats[j], s);
        atomicAdd(&stats[64 + j], s2);
    }
}

// ================= BN apply (+ optional ReLU) =================

__global__ __launch_bounds__(256) void bn_apply(const float* __restrict__ Y,
                                                const float* __restrict__ stats,
                                                const float* __restrict__ gamma,
                                                const float* __restrict__ beta,
                                                float* __restrict__ X, int n, int relu) {
    size_t idx = (size_t)blockIdx.x * 256 + threadIdx.x;
    if (idx >= (size_t)n * 64) return;
    int j = (int)(idx & 63);
    float inv_n = 1.0f / (float)n;
    float mean = stats[j] * inv_n;
    float var = stats[64 + j] * inv_n - mean * mean;
    float sc = gamma[j] * rsqrtf(var + BN_EPS);
    float sh = beta[j] - mean * sc;
    float v = Y[idx] * sc + sh;
    if (relu) v = fmaxf(v, 0.f);
    X[idx] = v;
}

// ================= global mean pool =================

__global__ __launch_bounds__(256) void pool_sum(const float* __restrict__ H,
                                                const int* __restrict__ batch,
                                                float* __restrict__ out,
                                                float* __restrict__ cnt, int n) {
    const int CHUNK = 128;
    int w = blockIdx.x * 4 + (threadIdx.x >> 6);
    int lane = threadIdx.x & 63;
    int start = w * CHUNK;
    if (start >= n) return;
    int end = min(start + CHUNK, n);
    int cur = batch[start];
    float acc = 0.f;
    int run = 0;
    for (int i = start; i < end; ++i) {
        int g = batch[i];
        if (g != cur) {
            atomicAdd(&out[(size_t)cur * 64 + lane], acc);
            if (lane == 0) atomicAdd(&cnt[cur], (float)run);
            acc = 0.f;
            run = 0;
            cur = g;
        }
        acc += H[(size_t)i * 64 + lane];
        run++;
    }
    atomicAdd(&out[(size_t)cur * 64 + lane], acc);
    if (lane == 0) atomicAdd(&cnt[cur], (float)run);
}

__global__ void pool_div(float* __restrict__ out, const float* __restrict__ cnt, int G) {
    int idx = blockIdx.x * 256 + threadIdx.x;
    if (idx < G * 64) out[idx] /= fmaxf(cnt[idx >> 6], 1.0f);
}

// ================= launch =================

extern "C" void kernel_launch(void* const* d_in, const int* in_sizes, int n_in,
                              void* d_out, int out_size, void* d_ws, size_t ws_size,
                              hipStream_t stream) {
    const float* x     = (const float*)d_in[0];
    const int*   ei    = (const int*)d_in[1];
    const int*   batch = (const int*)d_in[2];
    const float* Wl[3] = {(const float*)d_in[3], (const float*)d_in[7], (const float*)d_in[11]};
    const float* gl[3] = {(const float*)d_in[5], (const float*)d_in[9], (const float*)d_in[13]};
    const float* bl[3] = {(const float*)d_in[6], (const float*)d_in[10], (const float*)d_in[14]};
    float* out = (float*)d_out;

    int E = in_sizes[1] / 2;
    int n = in_sizes[0] / 64;
    int G = out_size / 64;
    const int* src = ei;
    const int* dst = ei + E;

    // ---- workspace carve-up ----
    char* ws = (char*)d_ws;
    size_t off = 0;
    auto carve = [&](size_t bytes) {
        void* p = ws + off;
        off += (bytes + 255) & ~(size_t)255;
        return p;
    };
    float* dinv   = (float*)carve((size_t)n * 4);
    float* stats  = (float*)carve(128 * 4);
    float* cnt_g  = (float*)carve((size_t)G * 4);
    float* bufA   = (float*)carve((size_t)n * 64 * 4);
    float* bufB   = (float*)carve((size_t)n * 64 * 4);
    int*   cnt_i  = (int*)carve((size_t)n * 4);
    int*   rp     = (int*)carve(((size_t)n + 1) * 4);
    int*   cursor = (int*)carve((size_t)n * 4);
    int*   bsum   = (int*)carve(256 * 4);
    int*   col    = (int*)carve((size_t)E * 4);

    int nb = (n + 255) / 256;  // scan blocks (n<=65536 -> nb<=256)

    // ---- CSR build + dinv ----
    zero_i32<<<nb, 256, 0, stream>>>(cnt_i, n);
    hist_dst<<<(E + 255) / 256, 256, 0, stream>>>(dst, cnt_i, E);
    make_dinv<<<nb, 256, 0, stream>>>(cnt_i, dinv, n);
    scan1<<<nb, 256, 0, stream>>>(cnt_i, rp, bsum, n);
    scan2<<<1, 256, 0, stream>>>(bsum, nb);
    scan3<<<nb, 256, 0, stream>>>(rp, bsum, cursor, n, E);
    scatter_col<<<(E + 255) / 256, 256, 0, stream>>>(src, dst, cursor, col, E);

    // ---- 3 GCN layers ----
    const float* cur = x;
    for (int l = 0; l < 3; ++l) {
        float* Hs = (l & 1) ? bufB : bufA;
        float* Y  = (l & 1) ? bufA : bufB;
        gemm64<<<(n + 15) / 16, 256, 0, stream>>>(cur, Wl[l], dinv, Hs, n);
        agg<<<(n + 3) / 4, 256, 0, stream>>>(Hs, rp, col, dinv, Y, n);
        hipMemsetAsync(stats, 0, 128 * sizeof(float), stream);
        bn_stats<<<256, 256, 0, stream>>>(Y, stats, n);
        bn_apply<<<(int)(((size_t)n * 64 + 255) / 256), 256, 0, stream>>>(
            Y, stats, gl[l], bl[l], Hs, n, l < 2 ? 1 : 0);
        cur = Hs;
    }

    // ---- pool ----
    hipMemsetAsync(out, 0, (size_t)G * 64 * sizeof(float), stream);
    hipMemsetAsync(cnt_g, 0, (size_t)G * sizeof(float), stream);
    int waves = (n + 127) / 128;
    pool_sum<<<(waves + 3) / 4, 256, 0, stream>>>(cur, batch, out, cnt_g, n);
    pool_div<<<(G * 64 + 255) / 256, 256, 0, stream>>>(out, cnt_g, G);
}

// Round 3
// 438.402 us; speedup vs baseline: 2.2265x; 1.3643x over previous
//
#include <hip/hip_runtime.h>

#define BN_EPS 1e-5f

// ================= CSR build =================

__global__ void zero_i32(int* __restrict__ p, int n) {
    int i = blockIdx.x * 256 + threadIdx.x;
    if (i < n) p[i] = 0;
}

__global__ void hist_dst(const int* __restrict__ dst, int* __restrict__ cnt, int E) {
    int e = blockIdx.x * 256 + threadIdx.x;
    if (e < E) atomicAdd(&cnt[dst[e]], 1);
}

__global__ void make_dinv(const int* __restrict__ cnt, float* __restrict__ dinv, int n) {
    int i = blockIdx.x * 256 + threadIdx.x;
    if (i < n) dinv[i] = rsqrtf(1.0f + (float)cnt[i]);
}

__global__ __launch_bounds__(256) void scan1(const int* __restrict__ cnt, int* __restrict__ rp,
                                             int* __restrict__ bsum, int n) {
    __shared__ int s[256];
    int i = blockIdx.x * 256 + threadIdx.x;
    int v = (i < n) ? cnt[i] : 0;
    s[threadIdx.x] = v;
    __syncthreads();
    for (int off = 1; off < 256; off <<= 1) {
        int t = (threadIdx.x >= off) ? s[threadIdx.x - off] : 0;
        __syncthreads();
        s[threadIdx.x] += t;
        __syncthreads();
    }
    if (i < n) rp[i] = s[threadIdx.x] - v;
    if (threadIdx.x == 255) bsum[blockIdx.x] = s[255];
}

__global__ __launch_bounds__(256) void scan2(int* __restrict__ bsum, int nb) {
    __shared__ int s[256];
    int v = (threadIdx.x < nb) ? bsum[threadIdx.x] : 0;
    s[threadIdx.x] = v;
    __syncthreads();
    for (int off = 1; off < 256; off <<= 1) {
        int t = (threadIdx.x >= off) ? s[threadIdx.x - off] : 0;
        __syncthreads();
        s[threadIdx.x] += t;
        __syncthreads();
    }
    if (threadIdx.x < nb) bsum[threadIdx.x] = s[threadIdx.x] - v;
}

__global__ void scan3(int* __restrict__ rp, const int* __restrict__ bsum,
                      int* __restrict__ cursor, int n, int E) {
    int i = blockIdx.x * 256 + threadIdx.x;
    if (i < n) {
        int v = rp[i] + bsum[blockIdx.x];
        rp[i] = v;
        cursor[i] = v;
    }
    if (i == 0) rp[n] = E;
}

__global__ void scatter_col(const int* __restrict__ src, const int* __restrict__ dst,
                            int* __restrict__ cursor, int* __restrict__ col, int E) {
    int e = blockIdx.x * 256 + threadIdx.x;
    if (e < E) {
        int pos = atomicAdd(&cursor[dst[e]], 1);
        col[pos] = src[e];
    }
}

// ================= GEMM v2: Hs = BNReLU(X) @ W * dinv[row] =================
// 64-row tile, 4 rows x 4 cols per thread, ds_read_b128 everywhere.
// LDS stride 68 floats: 4 simultaneous broadcast rows -> banks c, c+4, c+8, c+12.

#define SXS 68

__global__ __launch_bounds__(256) void gemm64_v2(const float* __restrict__ X,
                                                 const float* __restrict__ W,
                                                 const float* __restrict__ dinv,
                                                 const float* __restrict__ scsh,
                                                 int has_bn, int relu,
                                                 float* __restrict__ Hs, int n) {
    __shared__ float sX[64 * SXS];
    __shared__ float sW[64 * SXS];
    int t = threadIdx.x;
    int c4 = t & 15;   // column group: cols 4*c4 .. 4*c4+3
    int base = blockIdx.x * 64;

    // stage W (64x64)
    {
        const float4* W4 = (const float4*)W;
#pragma unroll
        for (int it = 0; it < 4; ++it) {
            int idx = it * 256 + t;
            int r = idx >> 4;
            float4 v = W4[r * 16 + c4];
            *(float4*)&sW[r * SXS + c4 * 4] = v;
        }
    }
    // stage X with optional BN(+ReLU) applied inline
    {
        const float4* X4 = (const float4*)X;
        float4 sc4, sh4;
        if (has_bn) {
            sc4 = ((const float4*)scsh)[c4];
            sh4 = ((const float4*)(scsh + 64))[c4];
        }
#pragma unroll
        for (int it = 0; it < 4; ++it) {
            int idx = it * 256 + t;
            int r = idx >> 4;
            int grow = base + r;
            float4 v = make_float4(0.f, 0.f, 0.f, 0.f);
            if (grow < n) v = X4[(size_t)grow * 16 + c4];
            if (has_bn) {
                v.x = fmaf(v.x, sc4.x, sh4.x);
                v.y = fmaf(v.y, sc4.y, sh4.y);
                v.z = fmaf(v.z, sc4.z, sh4.z);
                v.w = fmaf(v.w, sc4.w, sh4.w);
                if (relu) {
                    v.x = fmaxf(v.x, 0.f); v.y = fmaxf(v.y, 0.f);
                    v.z = fmaxf(v.z, 0.f); v.w = fmaxf(v.w, 0.f);
                }
            }
            *(float4*)&sX[r * SXS + c4 * 4] = v;
        }
    }
    __syncthreads();

    int rgrp = t >> 4;  // 0..15; rows rgrp + 16*ri
    float4 acc[4];
#pragma unroll
    for (int ri = 0; ri < 4; ++ri) acc[ri] = make_float4(0.f, 0.f, 0.f, 0.f);

#pragma unroll 4
    for (int k4 = 0; k4 < 16; ++k4) {
        float4 xv[4], wv[4];
#pragma unroll
        for (int ri = 0; ri < 4; ++ri)
            xv[ri] = *(const float4*)&sX[(rgrp + 16 * ri) * SXS + k4 * 4];
#pragma unroll
        for (int kk = 0; kk < 4; ++kk)
            wv[kk] = *(const float4*)&sW[(k4 * 4 + kk) * SXS + c4 * 4];
#pragma unroll
        for (int ri = 0; ri < 4; ++ri) {
            acc[ri].x = fmaf(xv[ri].x, wv[0].x, acc[ri].x);
            acc[ri].y = fmaf(xv[ri].x, wv[0].y, acc[ri].y);
            acc[ri].z = fmaf(xv[ri].x, wv[0].z, acc[ri].z);
            acc[ri].w = fmaf(xv[ri].x, wv[0].w, acc[ri].w);
            acc[ri].x = fmaf(xv[ri].y, wv[1].x, acc[ri].x);
            acc[ri].y = fmaf(xv[ri].y, wv[1].y, acc[ri].y);
            acc[ri].z = fmaf(xv[ri].y, wv[1].z, acc[ri].z);
            acc[ri].w = fmaf(xv[ri].y, wv[1].w, acc[ri].w);
            acc[ri].x = fmaf(xv[ri].z, wv[2].x, acc[ri].x);
            acc[ri].y = fmaf(xv[ri].z, wv[2].y, acc[ri].y);
            acc[ri].z = fmaf(xv[ri].z, wv[2].z, acc[ri].z);
            acc[ri].w = fmaf(xv[ri].z, wv[2].w, acc[ri].w);
            acc[ri].x = fmaf(xv[ri].w, wv[3].x, acc[ri].x);
            acc[ri].y = fmaf(xv[ri].w, wv[3].y, acc[ri].y);
            acc[ri].z = fmaf(xv[ri].w, wv[3].z, acc[ri].z);
            acc[ri].w = fmaf(xv[ri].w, wv[3].w, acc[ri].w);
        }
    }

#pragma unroll
    for (int ri = 0; ri < 4; ++ri) {
        int row = base + rgrp + 16 * ri;
        if (row < n) {
            float dv = dinv[row];
            float4 o = make_float4(acc[ri].x * dv, acc[ri].y * dv,
                                   acc[ri].z * dv, acc[ri].w * dv);
            *(float4*)&Hs[(size_t)row * 64 + c4 * 4] = o;
        }
    }
}

// ================= CSR gather-aggregate =================

__global__ __launch_bounds__(256) void agg(const float* __restrict__ Hs,
                                           const int* __restrict__ rp,
                                           const int* __restrict__ col,
                                           const float* __restrict__ dinv,
                                           float* __restrict__ Y, int n) {
    int d = blockIdx.x * 4 + (threadIdx.x >> 6);
    int lane = threadIdx.x & 63;
    if (d >= n) return;
    float acc = Hs[(size_t)d * 64 + lane];  // self loop
    int beg = rp[d], end = rp[d + 1];
    for (int b = beg; b < end; b += 64) {
        int m = min(64, end - b);
        int myidx = (lane < m) ? col[b + lane] : 0;
        int jj = 0;
        for (; jj + 3 < m; jj += 4) {
            int s0 = __shfl(myidx, jj, 64);
            int s1 = __shfl(myidx, jj + 1, 64);
            int s2 = __shfl(myidx, jj + 2, 64);
            int s3 = __shfl(myidx, jj + 3, 64);
            float v0 = Hs[(size_t)s0 * 64 + lane];
            float v1 = Hs[(size_t)s1 * 64 + lane];
            float v2 = Hs[(size_t)s2 * 64 + lane];
            float v3 = Hs[(size_t)s3 * 64 + lane];
            acc += v0 + v1 + v2 + v3;
        }
        for (; jj < m; ++jj) {
            int s0 = __shfl(myidx, jj, 64);
            acc += Hs[(size_t)s0 * 64 + lane];
        }
    }
    Y[(size_t)d * 64 + lane] = acc * dinv[d];
}

// ================= BN stats + finalize =================

__global__ __launch_bounds__(256) void bn_stats(const float* __restrict__ Y,
                                                float* __restrict__ stats, int n) {
    int t = threadIdx.x;
    int j = t & 63;
    int rg = t >> 6;
    float s = 0.f, s2 = 0.f;
    for (int i = blockIdx.x * 4 + rg; i < n; i += gridDim.x * 4) {
        float v = Y[(size_t)i * 64 + j];
        s += v;
        s2 += v * v;
    }
    __shared__ float red[256], red2[256];
    red[t] = s;
    red2[t] = s2;
    __syncthreads();
    if (rg == 0) {
        s  = red[j]  + red[64 + j]  + red[128 + j]  + red[192 + j];
        s2 = red2[j] + red2[64 + j] + red2[128 + j] + red2[192 + j];
        atomicAdd(&stats[j], s);
        atomicAdd(&stats[64 + j], s2);
    }
}

__global__ void bn_finalize(const float* __restrict__ stats,
                            const float* __restrict__ gamma,
                            const float* __restrict__ beta,
                            float* __restrict__ scsh, int n) {
    int j = threadIdx.x;  // 64 threads
    float inv_n = 1.0f / (float)n;
    float mean = stats[j] * inv_n;
    float var = stats[64 + j] * inv_n - mean * mean;
    float sc = gamma[j] * rsqrtf(var + BN_EPS);
    scsh[j] = sc;
    scsh[64 + j] = beta[j] - mean * sc;
}

// ================= global mean pool with fused BN =================

__global__ __launch_bounds__(256) void pool_sum_bn(const float* __restrict__ H,
                                                   const float* __restrict__ scsh,
                                                   const int* __restrict__ batch,
                                                   float* __restrict__ out,
                                                   float* __restrict__ cnt, int n) {
    const int CHUNK = 128;
    int w = blockIdx.x * 4 + (threadIdx.x >> 6);
    int lane = threadIdx.x & 63;
    int start = w * CHUNK;
    if (start >= n) return;
    float sc = scsh[lane], sh = scsh[64 + lane];
    int end = min(start + CHUNK, n);
    int cur = batch[start];
    float acc = 0.f;
    int run = 0;
    for (int i = start; i < end; ++i) {
        int g = batch[i];
        if (g != cur) {
            atomicAdd(&out[(size_t)cur * 64 + lane], acc);
            if (lane == 0) atomicAdd(&cnt[cur], (float)run);
            acc = 0.f;
            run = 0;
            cur = g;
        }
        acc += fmaf(H[(size_t)i * 64 + lane], sc, sh);
        run++;
    }
    atomicAdd(&out[(size_t)cur * 64 + lane], acc);
    if (lane == 0) atomicAdd(&cnt[cur], (float)run);
}

__global__ void pool_div(float* __restrict__ out, const float* __restrict__ cnt, int G) {
    int idx = blockIdx.x * 256 + threadIdx.x;
    if (idx < G * 64) out[idx] /= fmaxf(cnt[idx >> 6], 1.0f);
}

// ================= launch =================

extern "C" void kernel_launch(void* const* d_in, const int* in_sizes, int n_in,
                              void* d_out, int out_size, void* d_ws, size_t ws_size,
                              hipStream_t stream) {
    const float* x     = (const float*)d_in[0];
    const int*   ei    = (const int*)d_in[1];
    const int*   batch = (const int*)d_in[2];
    const float* Wl[3] = {(const float*)d_in[3], (const float*)d_in[7], (const float*)d_in[11]};
    const float* gl[3] = {(const float*)d_in[5], (const float*)d_in[9], (const float*)d_in[13]};
    const float* bl[3] = {(const float*)d_in[6], (const float*)d_in[10], (const float*)d_in[14]};
    float* out = (float*)d_out;

    int E = in_sizes[1] / 2;
    int n = in_sizes[0] / 64;
    int G = out_size / 64;
    const int* src = ei;
    const int* dst = ei + E;

    char* ws = (char*)d_ws;
    size_t off = 0;
    auto carve = [&](size_t bytes) {
        void* p = ws + off;
        off += (bytes + 255) & ~(size_t)255;
        return p;
    };
    float* dinv   = (float*)carve((size_t)n * 4);
    float* stats  = (float*)carve(128 * 4);
    float* scsh   = (float*)carve(128 * 4);
    float* cnt_g  = (float*)carve((size_t)G * 4);
    float* bufA   = (float*)carve((size_t)n * 64 * 4);  // Hs
    float* bufB   = (float*)carve((size_t)n * 64 * 4);  // Y
    int*   cnt_i  = (int*)carve((size_t)n * 4);
    int*   rp     = (int*)carve(((size_t)n + 1) * 4);
    int*   cursor = (int*)carve((size_t)n * 4);
    int*   bsum   = (int*)carve(256 * 4);
    int*   col    = (int*)carve((size_t)E * 4);

    int nb = (n + 255) / 256;

    // ---- CSR build + dinv ----
    zero_i32<<<nb, 256, 0, stream>>>(cnt_i, n);
    hist_dst<<<(E + 255) / 256, 256, 0, stream>>>(dst, cnt_i, E);
    make_dinv<<<nb, 256, 0, stream>>>(cnt_i, dinv, n);
    scan1<<<nb, 256, 0, stream>>>(cnt_i, rp, bsum, n);
    scan2<<<1, 256, 0, stream>>>(bsum, nb);
    scan3<<<nb, 256, 0, stream>>>(rp, bsum, cursor, n, E);
    scatter_col<<<(E + 255) / 256, 256, 0, stream>>>(src, dst, cursor, col, E);

    int gemm_grid = (n + 63) / 64;
    int agg_grid = (n + 3) / 4;

    // ---- 3 GCN layers: gemm(bufB->bufA), agg(bufA->bufB) ----
    const float* cur = x;
    for (int l = 0; l < 3; ++l) {
        gemm64_v2<<<gemm_grid, 256, 0, stream>>>(cur, Wl[l], dinv, scsh,
                                                 l > 0 ? 1 : 0, 1, bufA, n);
        agg<<<agg_grid, 256, 0, stream>>>(bufA, rp, col, dinv, bufB, n);
        hipMemsetAsync(stats, 0, 128 * sizeof(float), stream);
        bn_stats<<<256, 256, 0, stream>>>(bufB, stats, n);
        bn_finalize<<<1, 64, 0, stream>>>(stats, gl[l], bl[l], scsh, n);
        cur = bufB;
    }

    // ---- pool (BN3 fused, no relu) ----
    hipMemsetAsync(out, 0, (size_t)G * 64 * sizeof(float), stream);
    hipMemsetAsync(cnt_g, 0, (size_t)G * sizeof(float), stream);
    int waves = (n + 127) / 128;
    pool_sum_bn<<<(waves + 3) / 4, 256, 0, stream>>>(cur, scsh, batch, out, cnt_g, n);
    pool_div<<<(G * 64 + 255) / 256, 256, 0, stream>>>(out, cnt_g, G);
}